// Round 7
// baseline (3516.483 us; speedup 1.0000x reference)
//
#include <hip/hip_runtime.h>

#define S_LEN 8192
#define NH 16
#define NV 4
#define NB 512

typedef _Float16 h2 __attribute__((ext_vector_type(2)));

#define L2E  1.4426950408889634f   // log2(e)
#define L2E2 2.8853900817779268f   // 2*log2(e)

// ---------- DPP helpers ----------
template<int R>
__device__ __forceinline__ float rotf(float v) {
    return __int_as_float(__builtin_amdgcn_mov_dpp(__float_as_int(v), 0x120 + R, 0xF, 0xF, true));
}
template<int R>
__device__ __forceinline__ h2 roth(h2 v) {    // row_ror:R on a packed half2 reg
    int i;
    __builtin_memcpy(&i, &v, 4);
    i = __builtin_amdgcn_mov_dpp(i, 0x120 + R, 0xF, 0xF, true);
    h2 o;
    __builtin_memcpy(&o, &i, 4);
    return o;
}
__device__ __forceinline__ float qxor1(float v) {  // quad_perm [1,0,3,2]
    return __int_as_float(__builtin_amdgcn_mov_dpp(__float_as_int(v), 0xB1, 0xF, 0xF, true));
}
__device__ __forceinline__ float qxor2(float v) {  // quad_perm [2,3,0,1]
    return __int_as_float(__builtin_amdgcn_mov_dpp(__float_as_int(v), 0x4E, 0xF, 0xF, true));
}
__device__ __forceinline__ float qxor3(float v) {  // quad_perm [3,2,1,0]
    return __int_as_float(__builtin_amdgcn_mov_dpp(__float_as_int(v), 0x1B, 0xF, 0xF, true));
}

__device__ __forceinline__ float fex2(float x) { return __builtin_amdgcn_exp2f(x); }
__device__ __forceinline__ float frcp(float x) { return __builtin_amdgcn_rcpf(x); }
// pre-scaled sigmoid: x already multiplied by log2(e) (folded into weights)
__device__ __forceinline__ float fsig2(float x) { return frcp(1.0f + fex2(-x)); }
__device__ __forceinline__ float4 ld4(const float* p) { return *(const float4*)p; }

// Pack two f32 to half2 via v_cvt_pkrtz_f16_f32.
__device__ __forceinline__ h2 pkh(float a, float b) {
    auto t = __builtin_amdgcn_cvt_pkrtz(a, b);
    h2 o;
    __builtin_memcpy(&o, &t, 4);
    return o;
}

// Half-broadcast-exchange (lanes i <-> i+32): after call lo = lower half's
// value everywhere, hi = upper half's value everywhere. (HW-verified)
__device__ __forceinline__ void bcast32(float v, float& lo, float& hi) {
    lo = v;
    asm("v_permlane32_swap_b32 %0, %1" : "+v"(lo), "+v"(v));
    hi = v;
}
// Row-pair broadcast-exchange (lanes i <-> i+16 within each half):
// e = even-row's value in both rows of the pair, o = odd-row's value. (HW-verified)
__device__ __forceinline__ void bcast16(float v, float& e, float& o) {
    e = v;
    asm("v_permlane16_swap_b32 %0, %1" : "+v"(e), "+v"(v));
    o = v;
}

// hp[k] = packed (h[(j+sgn*2k)&15], h[(j+sgn*(2k+1))&15]) as half2.
#define FILL_HP16(hp, h)                                      \
    do {                                                      \
        h2 p0_ = pkh((h), rotf<1>(h));                        \
        hp[0] = p0_;                                          \
        hp[1] = roth<2>(p0_);                                 \
        hp[2] = roth<4>(p0_);                                 \
        hp[3] = roth<6>(p0_);                                 \
        hp[4] = roth<8>(p0_);                                 \
        hp[5] = roth<10>(p0_);                                \
        hp[6] = roth<12>(p0_);                                \
        hp[7] = roth<14>(p0_);                                \
    } while (0)

// 16-dot via v_dot2_f32_f16: 8 dot2 + 1 add, TWO chains of depth 4.
__device__ __forceinline__ float dotd2(const h2* __restrict__ w, const h2* hp, float start) {
    float a = __builtin_amdgcn_fdot2(w[0], hp[0], start, false);
    float b = __builtin_amdgcn_fdot2(w[1], hp[1], 0.0f, false);
    a = __builtin_amdgcn_fdot2(w[2], hp[2], a, false);
    b = __builtin_amdgcn_fdot2(w[3], hp[3], b, false);
    a = __builtin_amdgcn_fdot2(w[4], hp[4], a, false);
    b = __builtin_amdgcn_fdot2(w[5], hp[5], b, false);
    a = __builtin_amdgcn_fdot2(w[6], hp[6], a, false);
    b = __builtin_amdgcn_fdot2(w[7], hp[7], b, false);
    return a + b;
}
// 20-dot (16 h + 4 x): 10 dot2 + 1 add, two chains of depth 5.
__device__ __forceinline__ float dotd2x(const h2* __restrict__ w, const h2* hp, float start) {
    float a = __builtin_amdgcn_fdot2(w[0], hp[0], start, false);
    float b = __builtin_amdgcn_fdot2(w[1], hp[1], 0.0f, false);
    a = __builtin_amdgcn_fdot2(w[2], hp[2], a, false);
    b = __builtin_amdgcn_fdot2(w[3], hp[3], b, false);
    a = __builtin_amdgcn_fdot2(w[4], hp[4], a, false);
    b = __builtin_amdgcn_fdot2(w[5], hp[5], b, false);
    a = __builtin_amdgcn_fdot2(w[6], hp[6], a, false);
    b = __builtin_amdgcn_fdot2(w[7], hp[7], b, false);
    a = __builtin_amdgcn_fdot2(w[8], hp[8], a, false);
    b = __builtin_amdgcn_fdot2(w[9], hp[9], b, false);
    return a + b;
}

// ======================= FUSED ENC+DEC, 1 element/wave, 4 roles =======================
// 512 blocks x 64 threads. Latency-path-optimized variant:
//   enc rows: 0 = r' (h+x)   1 = hn (h)   2 = z' (h+x)   3 = inn (x)
//   dec rows: 0 = r' (h)     1 = hn (h)   2 = z' (h)     3 = hn DUPLICATE
// Dec out-logits (oa) are computed LOCALLY on every lane (own q), so the
// argmax tree needs no crossings and overlaps with the r'/z' exchange.
// All cross-lane exchanges happen BEFORE the sigmoids; both sigmoids are
// computed locally on every lane (removes the mid-transcendental crossing).
__global__ __launch_bounds__(64, 1) void rnn_kernel(
    const float* __restrict__ gt,
    const float* __restrict__ eWih, const float* __restrict__ eWhh,
    const float* __restrict__ ebih, const float* __restrict__ ebhh,
    const float* __restrict__ dWih, const float* __restrict__ dWhh,
    const float* __restrict__ dbih, const float* __restrict__ dbhh,
    const float* __restrict__ oW,  const float* __restrict__ ob,
    float* __restrict__ outs)                 // [NB][S_LEN][4] logit scratch
{
    const int lane = threadIdx.x;
    const int j    = lane & 15;
    const int q    = j & 3;
    const int row  = lane >> 4;               // 0..3 = gate role
    const int b    = blockIdx.x;

    int probe = __builtin_amdgcn_mov_dpp(j, 0x121, 0xF, 0xF, true);
    const int sgn = (probe == ((j + 1) & 15)) ? 1 : -1;

    float h = 0.0f;

    // ---------------- encoder phase ----------------
    {
        const float* gb = gt + (size_t)b * (NV * S_LEN);
        h2 w[10];
        float start;
        {
            const int g  = (row == 0) ? 0 : (row == 2) ? 1 : 2;   // r,z,n row-block
            const float schh = (row == 0 || row == 2) ? L2E : (row == 1 ? L2E2 : 0.0f);
            const float scih = (row == 0 || row == 2) ? L2E : (row == 3 ? L2E2 : 0.0f);
#pragma unroll
            for (int p = 0; p < 8; ++p) {
                int k0 = (j + sgn * (2 * p)) & 15;
                int k1 = (j + sgn * (2 * p + 1)) & 15;
                w[p] = (h2){(_Float16)(schh * eWhh[(g * NH + j) * NH + k0]),
                            (_Float16)(schh * eWhh[(g * NH + j) * NH + k1])};
            }
#pragma unroll
            for (int p = 0; p < 2; ++p) {     // x-part, k16-19 (zero for row1)
                w[8 + p] = (h2){(_Float16)(scih * eWih[(g * NH + j) * NV + 2 * p]),
                                (_Float16)(scih * eWih[(g * NH + j) * NV + 2 * p + 1])};
            }
            start = (row == 0) ? L2E  * (ebih[j] + ebhh[j])
                  : (row == 2) ? L2E  * (ebih[NH + j] + ebhh[NH + j])
                  : (row == 1) ? L2E2 * ebhh[2 * NH + j]
                               : L2E2 * ebih[2 * NH + j];
        }

        auto estep = [&](float x0, float x1, float x2, float x3) {
            h2 hp[10];
            FILL_HP16(hp, h);
            hp[8] = pkh(x0, x1);
            hp[9] = pkh(x2, x3);
            float v = dotd2x(w, hp, start);
            float e, o_;
            bcast16(v, e, o_);                 // lo:(r',hn)  hi:(z',inn)
            float rp, zp, hn_, inn_;
            bcast32(e,  rp,  zp);              // r', z' everywhere (pre-sigmoid)
            bcast32(o_, hn_, inn_);            // hn, inn everywhere
            float r  = fsig2(rp);              // both sigmoids local — no
            float z  = fsig2(zp);              // crossing between trans ops
            float y  = fmaf(r, hn_, inn_);     // = 2*log2(e) * (inn + r*hn)
            float w2 = fsig2(y);               // = sigma(2y) -> tanh blend
            float t2 = fmaf(-2.0f, z, 2.0f);
            float tb = fmaf(z, h, z - 1.0f);
            h = fmaf(w2, t2, tb);
        };

        float4 A0 = ld4(gb + 0 * S_LEN), A1 = ld4(gb + 1 * S_LEN),
               A2 = ld4(gb + 2 * S_LEN), A3 = ld4(gb + 3 * S_LEN);
        float4 B0 = ld4(gb + 0 * S_LEN + 4), B1 = ld4(gb + 1 * S_LEN + 4),
               B2 = ld4(gb + 2 * S_LEN + 4), B3 = ld4(gb + 3 * S_LEN + 4);
        for (int t = 0; t < S_LEN; t += 8) {
            estep(A0.x, A1.x, A2.x, A3.x);
            estep(A0.y, A1.y, A2.y, A3.y);
            estep(A0.z, A1.z, A2.z, A3.z);
            estep(A0.w, A1.w, A2.w, A3.w);
            int ta = t + 8;  if (ta > S_LEN - 4) ta = S_LEN - 4;
            A0 = ld4(gb + 0 * S_LEN + ta); A1 = ld4(gb + 1 * S_LEN + ta);
            A2 = ld4(gb + 2 * S_LEN + ta); A3 = ld4(gb + 3 * S_LEN + ta);
            estep(B0.x, B1.x, B2.x, B3.x);
            estep(B0.y, B1.y, B2.y, B3.y);
            estep(B0.z, B1.z, B2.z, B3.z);
            estep(B0.w, B1.w, B2.w, B3.w);
            int tb2 = t + 12; if (tb2 > S_LEN - 4) tb2 = S_LEN - 4;
            B0 = ld4(gb + 0 * S_LEN + tb2); B1 = ld4(gb + 1 * S_LEN + tb2);
            B2 = ld4(gb + 2 * S_LEN + tb2); B3 = ld4(gb + 3 * S_LEN + tb2);
        }
    }

    // ---------------- decoder phase ----------------
    // Gate dot per row (rows 1 AND 3 = hn, duplicated) + LOCAL out-dot on
    // every lane. ow[] bits identical to the old row3 computation.
    h2 w[8], ow[8];
    float start;
    {
        const int g  = (row == 0) ? 0 : (row == 2) ? 1 : 2;   // rows 1,3 -> n
        const float schh = (row == 0 || row == 2) ? L2E : L2E2;
#pragma unroll
        for (int p = 0; p < 8; ++p) {
            int k0 = (j + sgn * (2 * p)) & 15;
            int k1 = (j + sgn * (2 * p + 1)) & 15;
            w[p]  = (h2){(_Float16)(schh * dWhh[(g * NH + j) * NH + k0]),
                         (_Float16)(schh * dWhh[(g * NH + j) * NH + k1])};
            ow[p] = (h2){(_Float16)oW[q * NH + k0], (_Float16)oW[q * NH + k1]};
        }
        start = (row == 0) ? L2E  * (dbih[j] + dbhh[j])
              : (row == 2) ? L2E  * (dbih[NH + j] + dbhh[NH + j])
                           : L2E2 * dbhh[2 * NH + j];          // rows 1,3
    }
    const float bNi  = dbih[2 * NH + j];
    const float bNiS = L2E2 * bNi;
    const float obq  = ob[q];
    // per-class one-hot x-terms, REGISTER order m (class = m ^ q), pre-scaled.
    float SAr[NV], SAz[NV], KN[NV];
#pragma unroll
    for (int m = 0; m < NV; ++m) {
        int c = m ^ q;
        SAr[m] = L2E  * dWih[(0 * NH + j) * NV + c];
        SAz[m] = L2E  * dWih[(1 * NH + j) * NV + c];
        KN[m]  = L2E2 * (bNi + dWih[(2 * NH + j) * NV + c]);
    }

    int oidx = (b << 15) + q;                 // (b*S_LEN + 0)*4 + q
    const bool storer = (lane < 4);           // lanes 0..3: q = lane, own oa

    auto dstep = [&](int koff) {
        h2 hp[8];
        FILL_HP16(hp, h);
        float vg = dotd2(w,  hp, start);      // r' | hn | z' | hn
        float oa = dotd2(ow, hp, obq);        // LOCAL logits out[q] of step t-1
        if (storer) outs[oidx + koff] = oa;
        float e, hn_;
        bcast16(vg, e, hn_);                  // e = r'|z' per half; hn_ local both halves
        float rp, zp;
        bcast32(e, rp, zp);                   // r', z' everywhere (pre-sigmoid)
        // argmax from LOCAL oa — zero crossings, overlaps the exchanges above
        float ob_ = qxor1(oa);                // out[q^1]
        float oc_ = qxor2(oa);                // out[q^2]
        float od_ = qxor3(oa);                // out[q^3]
        bool cA = ob_ > oa;  float mA = fmaxf(oa, ob_);
        bool cB = od_ > oc_; float mB = fmaxf(oc_, od_);
        bool hi_ = mB > mA;
        float KR  = hi_ ? (cB ? SAr[3] : SAr[2]) : (cA ? SAr[1] : SAr[0]);
        float KZ  = hi_ ? (cB ? SAz[3] : SAz[2]) : (cA ? SAz[1] : SAz[0]);
        float KN_ = hi_ ? (cB ? KN[3]  : KN[2])  : (cA ? KN[1]  : KN[0]);
        float r   = fsig2(rp + KR);           // both sigmoids local
        float z   = fsig2(zp + KZ);
        float y   = fmaf(r, hn_, KN_);
        float w2  = fsig2(y);
        float t2  = fmaf(-2.0f, z, 2.0f);
        float tb  = fmaf(z, h, z - 1.0f);
        h = fmaf(w2, t2, tb);
    };

    // t = 0: x0 = zeros — no K terms, no store, no argmax
    {
        h2 hp[8];
        FILL_HP16(hp, h);
        float vg = dotd2(w, hp, start);
        float e, hn_;
        bcast16(vg, e, hn_);
        float rp, zp;
        bcast32(e, rp, zp);
        float r  = fsig2(rp);
        float z  = fsig2(zp);
        float y  = fmaf(r, hn_, bNiS);
        float w2 = fsig2(y);
        float t2 = fmaf(-2.0f, z, 2.0f);
        float tb = fmaf(z, h, z - 1.0f);
        h = fmaf(w2, t2, tb);
    }
    // t = 1..8191: 8191 dsteps = 1023 x 8 + 7
    for (int u = 0; u < 8184; u += 8) {
#pragma unroll
        for (int k = 0; k < 8; ++k) dstep(k * 4);
        oidx += 32;
    }
#pragma unroll
    for (int k = 0; k < 7; ++k) dstep(k * 4);
    oidx += 28;

    // tail: logits of final step (t = S-1) — local dot, no crossings at all
    {
        h2 hp[8];
        FILL_HP16(hp, h);
        float oa = dotd2(ow, hp, obq);
        if (storer) outs[oidx] = oa;
    }
}

// Epilogue: NLL over all (b,t) from stored logits + gt targets; zero the scratch.
__global__ __launch_bounds__(1024) void loss_kernel(
    const float* __restrict__ gt, float* __restrict__ outs, float* __restrict__ loss)
{
    int tid = blockIdx.x * 1024 + threadIdx.x;   // over NB*S_LEN
    int t = tid & (S_LEN - 1);
    int b = tid >> 13;
    float4 o = *(const float4*)(outs + (size_t)tid * 4);
    const float* g = gt + (size_t)b * (NV * S_LEN) + t;
    float p0 = g[0], p1 = g[S_LEN], p2 = g[2 * S_LEN], p3 = g[3 * S_LEN];
    int tg = (p1 > p0) ? 1 : 0;  float bm = fmaxf(p0, p1);
    tg = (p2 > bm) ? 2 : tg;     bm = fmaxf(p2, bm);
    tg = (p3 > bm) ? 3 : tg;
    float vt = (tg & 1) ? ((tg & 2) ? o.w : o.y) : ((tg & 2) ? o.z : o.x);
    float mx = fmaxf(fmaxf(o.x, o.y), fmaxf(o.z, o.w));
    float ss = __expf(o.x - mx) + __expf(o.y - mx) + __expf(o.z - mx) + __expf(o.w - mx);
    float v  = (mx - vt) + __logf(ss);
    *(float4*)(outs + (size_t)tid * 4) = make_float4(0.f, 0.f, 0.f, 0.f);
#pragma unroll
    for (int d = 1; d < 64; d <<= 1) v += __shfl_xor(v, d, 64);
    __shared__ float sm[16];
    int w = threadIdx.x >> 6;
    if ((threadIdx.x & 63) == 0) sm[w] = v;
    __syncthreads();
    if (threadIdx.x < 16) {
        float s = sm[threadIdx.x];
#pragma unroll
        for (int d = 1; d < 16; d <<= 1) s += __shfl_xor(s, d, 64);
        if (threadIdx.x == 0) atomicAdd(loss, s * (1.0f / NB));
    }
}

extern "C" void kernel_launch(void* const* d_in, const int* in_sizes, int n_in,
                              void* d_out, int out_size, void* d_ws, size_t ws_size,
                              hipStream_t stream) {
    (void)in_sizes; (void)n_in; (void)d_ws; (void)ws_size; (void)out_size;
    const float* gt   = (const float*)d_in[0];
    const float* eWih = (const float*)d_in[1];
    const float* eWhh = (const float*)d_in[2];
    const float* ebih = (const float*)d_in[3];
    const float* ebhh = (const float*)d_in[4];
    const float* dWih = (const float*)d_in[5];
    const float* dWhh = (const float*)d_in[6];
    const float* dbih = (const float*)d_in[7];
    const float* dbhh = (const float*)d_in[8];
    const float* oW   = (const float*)d_in[9];
    const float* ob   = (const float*)d_in[10];

    float* out  = (float*)d_out;       // out[0] = loss
    float* outs = out + 1;             // [NB][S_LEN][4] logit scratch == output_batch region
    (void)hipMemsetAsync(d_out, 0, sizeof(float), stream);   // zero loss only
    rnn_kernel<<<NB, 64, 0, stream>>>(gt, eWih, eWhh, ebih, ebhh,
                                      dWih, dWhh, dbih, dbhh, oW, ob, outs);
    loss_kernel<<<(NB * S_LEN) / 1024, 1024, 0, stream>>>(gt, outs, out);
}

// Round 8
// 2998.200 us; speedup vs baseline: 1.1729x; 1.1729x over previous
//
#include <hip/hip_runtime.h>

#define S_LEN 8192
#define NH 16
#define NV 4
#define NB 512

typedef _Float16 h2 __attribute__((ext_vector_type(2)));

#define L2E  1.4426950408889634f   // log2(e)
#define L2E2 2.8853900817779268f   // 2*log2(e)

// ---------- DPP helpers ----------
template<int R>
__device__ __forceinline__ float rotf(float v) {
    return __int_as_float(__builtin_amdgcn_mov_dpp(__float_as_int(v), 0x120 + R, 0xF, 0xF, true));
}
template<int R>
__device__ __forceinline__ h2 roth(h2 v) {    // row_ror:R on a packed half2 reg
    int i;
    __builtin_memcpy(&i, &v, 4);
    i = __builtin_amdgcn_mov_dpp(i, 0x120 + R, 0xF, 0xF, true);
    h2 o;
    __builtin_memcpy(&o, &i, 4);
    return o;
}
__device__ __forceinline__ float qxor1(float v) {  // quad_perm [1,0,3,2]
    return __int_as_float(__builtin_amdgcn_mov_dpp(__float_as_int(v), 0xB1, 0xF, 0xF, true));
}
__device__ __forceinline__ float qxor2(float v) {  // quad_perm [2,3,0,1]
    return __int_as_float(__builtin_amdgcn_mov_dpp(__float_as_int(v), 0x4E, 0xF, 0xF, true));
}
__device__ __forceinline__ float qxor3(float v) {  // quad_perm [3,2,1,0]
    return __int_as_float(__builtin_amdgcn_mov_dpp(__float_as_int(v), 0x1B, 0xF, 0xF, true));
}

__device__ __forceinline__ float fex2(float x) { return __builtin_amdgcn_exp2f(x); }
__device__ __forceinline__ float frcp(float x) { return __builtin_amdgcn_rcpf(x); }
// pre-scaled sigmoid: x already multiplied by log2(e) (folded into weights)
__device__ __forceinline__ float fsig2(float x) { return frcp(1.0f + fex2(-x)); }
__device__ __forceinline__ float4 ld4(const float* p) { return *(const float4*)p; }

// Pack two f32 to half2 via v_cvt_pkrtz_f16_f32.
__device__ __forceinline__ h2 pkh(float a, float b) {
    auto t = __builtin_amdgcn_cvt_pkrtz(a, b);
    h2 o;
    __builtin_memcpy(&o, &t, 4);
    return o;
}

// Half-broadcast-exchange (lanes i <-> i+32): after call lo = lower half's
// value everywhere, hi = upper half's value everywhere.
// Builtin form (schedulable, no copies/asm barrier) when available;
// lane semantics bit-identical to the asm fallback (HW-verified r2-r6).
__device__ __forceinline__ void bcast32(float v, float& lo, float& hi) {
#if __has_builtin(__builtin_amdgcn_permlane32_swap)
    auto p = __builtin_amdgcn_permlane32_swap(__float_as_uint(v), __float_as_uint(v), false, false);
    lo = __uint_as_float(p[0]);
    hi = __uint_as_float(p[1]);
#else
    lo = v;
    asm("v_permlane32_swap_b32 %0, %1" : "+v"(lo), "+v"(v));
    hi = v;
#endif
}
// Row-pair broadcast-exchange (lanes i <-> i+16 within each half):
// e = even-row's value in both rows of the pair, o = odd-row's value.
__device__ __forceinline__ void bcast16(float v, float& e, float& o) {
#if __has_builtin(__builtin_amdgcn_permlane16_swap)
    auto p = __builtin_amdgcn_permlane16_swap(__float_as_uint(v), __float_as_uint(v), false, false);
    e = __uint_as_float(p[0]);
    o = __uint_as_float(p[1]);
#else
    e = v;
    asm("v_permlane16_swap_b32 %0, %1" : "+v"(e), "+v"(v));
    o = v;
#endif
}

// hp[k] = packed (h[(j+sgn*2k)&15], h[(j+sgn*(2k+1))&15]) as half2.
#define FILL_HP16(hp, h)                                      \
    do {                                                      \
        h2 p0_ = pkh((h), rotf<1>(h));                        \
        hp[0] = p0_;                                          \
        hp[1] = roth<2>(p0_);                                 \
        hp[2] = roth<4>(p0_);                                 \
        hp[3] = roth<6>(p0_);                                 \
        hp[4] = roth<8>(p0_);                                 \
        hp[5] = roth<10>(p0_);                                \
        hp[6] = roth<12>(p0_);                                \
        hp[7] = roth<14>(p0_);                                \
    } while (0)

// single-chain dots (r5 form — best measured; bit-family absmax 64)
__device__ __forceinline__ float dot8s(const h2* __restrict__ w, const h2* hp, float start) {
    float a = start;
#pragma unroll
    for (int p = 0; p < 8; ++p) a = __builtin_amdgcn_fdot2(w[p], hp[p], a, false);
    return a;
}
__device__ __forceinline__ float dot10s(const h2* __restrict__ w, const h2* hp, float start) {
    float a = start;
#pragma unroll
    for (int p = 0; p < 10; ++p) a = __builtin_amdgcn_fdot2(w[p], hp[p], a, false);
    return a;
}

// ======================= FUSED ENC+DEC, 1 element/wave, 4 roles =======================
// 512 blocks x 64 threads. Each 16-lane row computes ONE dot per step.
//   enc rows: 0 = r' (h+x, L2E)   1 = hn (h, L2E2)   2 = z' (h+x, L2E)  3 = inn (x, L2E2)
//   dec rows: 0 = r' (h, L2E)     1 = hn (h, L2E2)   2 = z' (h, L2E)    3 = oa (oW, exact)
// bcast16 -> e = {r' | z'} per half, o = {hn | inn-or-oa}; one fsig2 covers r AND z.
__global__ __launch_bounds__(64, 1) void rnn_kernel(
    const float* __restrict__ gt,
    const float* __restrict__ eWih, const float* __restrict__ eWhh,
    const float* __restrict__ ebih, const float* __restrict__ ebhh,
    const float* __restrict__ dWih, const float* __restrict__ dWhh,
    const float* __restrict__ dbih, const float* __restrict__ dbhh,
    const float* __restrict__ oW,  const float* __restrict__ ob,
    float* __restrict__ outs)                 // [NB][S_LEN][4] logit scratch
{
    const int lane = threadIdx.x;
    const int j    = lane & 15;
    const int q    = j & 3;
    const int row  = lane >> 4;               // 0..3 = gate role
    const bool loH = (lane < 32);
    const int b    = blockIdx.x;

    int probe = __builtin_amdgcn_mov_dpp(j, 0x121, 0xF, 0xF, true);
    const int sgn = (probe == ((j + 1) & 15)) ? 1 : -1;

    float h = 0.0f;

    // ---------------- encoder phase ----------------
    {
        const float* gb = gt + (size_t)b * (NV * S_LEN);
        h2 w[10];
        float start;
        {
            const int g  = (row == 0) ? 0 : (row == 2) ? 1 : 2;   // r,z,n row-block
            const float schh = (row == 0 || row == 2) ? L2E : (row == 1 ? L2E2 : 0.0f);
            const float scih = (row == 0 || row == 2) ? L2E : (row == 3 ? L2E2 : 0.0f);
#pragma unroll
            for (int p = 0; p < 8; ++p) {
                int k0 = (j + sgn * (2 * p)) & 15;
                int k1 = (j + sgn * (2 * p + 1)) & 15;
                w[p] = (h2){(_Float16)(schh * eWhh[(g * NH + j) * NH + k0]),
                            (_Float16)(schh * eWhh[(g * NH + j) * NH + k1])};
            }
#pragma unroll
            for (int p = 0; p < 2; ++p) {     // x-part, k16-19 (zero for row1)
                w[8 + p] = (h2){(_Float16)(scih * eWih[(g * NH + j) * NV + 2 * p]),
                                (_Float16)(scih * eWih[(g * NH + j) * NV + 2 * p + 1])};
            }
            start = (row == 0) ? L2E  * (ebih[j] + ebhh[j])
                  : (row == 2) ? L2E  * (ebih[NH + j] + ebhh[NH + j])
                  : (row == 1) ? L2E2 * ebhh[2 * NH + j]
                               : L2E2 * ebih[2 * NH + j];
        }

        auto estep = [&](float x0, float x1, float x2, float x3) {
            h2 hp[10];
            FILL_HP16(hp, h);
            hp[8] = pkh(x0, x1);
            hp[9] = pkh(x2, x3);
            float v = dot10s(w, hp, start);
            float e, o_;
            bcast16(v, e, o_);                 // e = {r'|z'}, o_ = {hn|inn}
            float hn_, inn_;
            bcast32(o_, hn_, inn_);
            float sg = fsig2(e);               // lo: r, hi: z (shared trans)
            float r, z;
            bcast32(sg, r, z);
            float y  = fmaf(r, hn_, inn_);     // = 2*log2(e) * (inn + r*hn)
            float w2 = fsig2(y);               // = sigma(2y) -> tanh blend
            float t2 = fmaf(-2.0f, z, 2.0f);
            float tb = fmaf(z, h, z - 1.0f);
            h = fmaf(w2, t2, tb);
        };

        float4 A0 = ld4(gb + 0 * S_LEN), A1 = ld4(gb + 1 * S_LEN),
               A2 = ld4(gb + 2 * S_LEN), A3 = ld4(gb + 3 * S_LEN);
        float4 B0 = ld4(gb + 0 * S_LEN + 4), B1 = ld4(gb + 1 * S_LEN + 4),
               B2 = ld4(gb + 2 * S_LEN + 4), B3 = ld4(gb + 3 * S_LEN + 4);
        for (int t = 0; t < S_LEN; t += 8) {
            estep(A0.x, A1.x, A2.x, A3.x);
            estep(A0.y, A1.y, A2.y, A3.y);
            estep(A0.z, A1.z, A2.z, A3.z);
            estep(A0.w, A1.w, A2.w, A3.w);
            int ta = t + 8;  if (ta > S_LEN - 4) ta = S_LEN - 4;
            A0 = ld4(gb + 0 * S_LEN + ta); A1 = ld4(gb + 1 * S_LEN + ta);
            A2 = ld4(gb + 2 * S_LEN + ta); A3 = ld4(gb + 3 * S_LEN + ta);
            estep(B0.x, B1.x, B2.x, B3.x);
            estep(B0.y, B1.y, B2.y, B3.y);
            estep(B0.z, B1.z, B2.z, B3.z);
            estep(B0.w, B1.w, B2.w, B3.w);
            int tb2 = t + 12; if (tb2 > S_LEN - 4) tb2 = S_LEN - 4;
            B0 = ld4(gb + 0 * S_LEN + tb2); B1 = ld4(gb + 1 * S_LEN + tb2);
            B2 = ld4(gb + 2 * S_LEN + tb2); B3 = ld4(gb + 3 * S_LEN + tb2);
        }
    }

    // ---------------- decoder phase ----------------
    h2 w[8];
    float start;
    {
        const int g  = (row == 0) ? 0 : (row == 2) ? 1 : 2;
        const float schh = (row == 0 || row == 2) ? L2E : (row == 1 ? L2E2 : 0.0f);
#pragma unroll
        for (int p = 0; p < 8; ++p) {
            int k0 = (j + sgn * (2 * p)) & 15;
            int k1 = (j + sgn * (2 * p + 1)) & 15;
            float w0 = (row == 3) ? oW[q * NH + k0] : schh * dWhh[(g * NH + j) * NH + k0];
            float w1 = (row == 3) ? oW[q * NH + k1] : schh * dWhh[(g * NH + j) * NH + k1];
            w[p] = (h2){(_Float16)w0, (_Float16)w1};
        }
        start = (row == 0) ? L2E  * (dbih[j] + dbhh[j])
              : (row == 2) ? L2E  * (dbih[NH + j] + dbhh[NH + j])
              : (row == 1) ? L2E2 * dbhh[2 * NH + j]
                           : ob[q];
    }
    const float bNi  = dbih[2 * NH + j];
    const float bNiS = L2E2 * bNi;
    // per-class one-hot x-terms, REGISTER order m (class = m ^ q), pre-scaled.
    // SA: lo-half = r-gate x-terms, hi-half = z-gate x-terms (sig sharing).
    const int gS = loH ? 0 : 1;
    float SA[NV], KN[NV];
#pragma unroll
    for (int m = 0; m < NV; ++m) {
        int c = m ^ q;
        SA[m] = L2E * dWih[(gS * NH + j) * NV + c];
        KN[m] = L2E2 * (bNi + dWih[(2 * NH + j) * NV + c]);
    }

    int oidx = (b << 15) + q;                 // (b*S_LEN + 0)*4 + q

    // koff is a compile-time literal under #pragma unroll: store address folds
    // into the global_store immediate offset (one oidx add per 16 steps).
    // Stores are UNCONDITIONAL: after bcast32, oa on lane l = out[l&3]; all
    // lanes with equal q write the same value to the same address (same
    // cacheline, one transaction) — removes the per-step exec-mask juggling.
    auto dstep = [&](int koff) {
        h2 hp[8];
        FILL_HP16(hp, h);
        float v = dot8s(w, hp, start);
        float e, o_;
        bcast16(v, e, o_);                    // e = {r'|z'}, o_ = {hn|oa}
        float hn_, oa;
        bcast32(o_, hn_, oa);
        outs[oidx + koff] = oa;               // logits of step t-1
        // argmax over the quad: 3 independent DPP fetches
        float ob_ = qxor1(oa);                // out[q^1]
        float oc_ = qxor2(oa);                // out[q^2]
        float od_ = qxor3(oa);                // out[q^3]
        bool cA = ob_ > oa;  float mA = fmaxf(oa, ob_);
        bool cB = od_ > oc_; float mB = fmaxf(oc_, od_);
        bool hi_ = mB > mA;
        float KA  = hi_ ? (cB ? SA[3] : SA[2]) : (cA ? SA[1] : SA[0]);
        float KN_ = hi_ ? (cB ? KN[3] : KN[2]) : (cA ? KN[1] : KN[0]);
        float sg  = fsig2(e + KA);            // lo: r, hi: z (shared trans)
        float r, z;
        bcast32(sg, r, z);
        float y   = fmaf(r, hn_, KN_);
        float w2  = fsig2(y);
        float t2  = fmaf(-2.0f, z, 2.0f);
        float tb  = fmaf(z, h, z - 1.0f);
        h = fmaf(w2, t2, tb);
    };

    // t = 0: x0 = zeros — no K terms, no store, no argmax
    {
        h2 hp[8];
        FILL_HP16(hp, h);
        float v = dot8s(w, hp, start);
        float e, o_;
        bcast16(v, e, o_);
        float hn_, oa;
        bcast32(o_, hn_, oa);
        float sg = fsig2(e);
        float r, z;
        bcast32(sg, r, z);
        float y  = fmaf(r, hn_, bNiS);
        float w2 = fsig2(y);
        float t2 = fmaf(-2.0f, z, 2.0f);
        float tb = fmaf(z, h, z - 1.0f);
        h = fmaf(w2, t2, tb);
    }
    // t = 1..8191: 8191 dsteps = 511 x 16 + 15
    for (int u = 0; u < 8176; u += 16) {
#pragma unroll
        for (int k = 0; k < 16; ++k) dstep(k * 4);
        oidx += 64;
    }
#pragma unroll
    for (int k = 0; k < 15; ++k) dstep(k * 4);
    oidx += 60;

    // tail: logits of final step (t = S-1)
    {
        h2 hp[8];
        FILL_HP16(hp, h);
        float v = dot8s(w, hp, start);
        float e, o_;
        bcast16(v, e, o_);
        float hn_, oa;
        bcast32(o_, hn_, oa);
        outs[oidx] = oa;
    }
}

// Epilogue: NLL over all (b,t) from stored logits + gt targets; zero the scratch.
__global__ __launch_bounds__(1024) void loss_kernel(
    const float* __restrict__ gt, float* __restrict__ outs, float* __restrict__ loss)
{
    int tid = blockIdx.x * 1024 + threadIdx.x;   // over NB*S_LEN
    int t = tid & (S_LEN - 1);
    int b = tid >> 13;
    float4 o = *(const float4*)(outs + (size_t)tid * 4);
    const float* g = gt + (size_t)b * (NV * S_LEN) + t;
    float p0 = g[0], p1 = g[S_LEN], p2 = g[2 * S_LEN], p3 = g[3 * S_LEN];
    int tg = (p1 > p0) ? 1 : 0;  float bm = fmaxf(p0, p1);
    tg = (p2 > bm) ? 2 : tg;     bm = fmaxf(p2, bm);
    tg = (p3 > bm) ? 3 : tg;
    float vt = (tg & 1) ? ((tg & 2) ? o.w : o.y) : ((tg & 2) ? o.z : o.x);
    float mx = fmaxf(fmaxf(o.x, o.y), fmaxf(o.z, o.w));
    float ss = __expf(o.x - mx) + __expf(o.y - mx) + __expf(o.z - mx) + __expf(o.w - mx);
    float v  = (mx - vt) + __logf(ss);
    *(float4*)(outs + (size_t)tid * 4) = make_float4(0.f, 0.f, 0.f, 0.f);
#pragma unroll
    for (int d = 1; d < 64; d <<= 1) v += __shfl_xor(v, d, 64);
    __shared__ float sm[16];
    int w = threadIdx.x >> 6;
    if ((threadIdx.x & 63) == 0) sm[w] = v;
    __syncthreads();
    if (threadIdx.x < 16) {
        float s = sm[threadIdx.x];
#pragma unroll
        for (int d = 1; d < 16; d <<= 1) s += __shfl_xor(s, d, 64);
        if (threadIdx.x == 0) atomicAdd(loss, s * (1.0f / NB));
    }
}

extern "C" void kernel_launch(void* const* d_in, const int* in_sizes, int n_in,
                              void* d_out, int out_size, void* d_ws, size_t ws_size,
                              hipStream_t stream) {
    (void)in_sizes; (void)n_in; (void)d_ws; (void)ws_size; (void)out_size;
    const float* gt   = (const float*)d_in[0];
    const float* eWih = (const float*)d_in[1];
    const float* eWhh = (const float*)d_in[2];
    const float* ebih = (const float*)d_in[3];
    const float* ebhh = (const float*)d_in[4];
    const float* dWih = (const float*)d_in[5];
    const float* dWhh = (const float*)d_in[6];
    const float* dbih = (const float*)d_in[7];
    const float* dbhh = (const float*)d_in[8];
    const float* oW   = (const float*)d_in[9];
    const float* ob   = (const float*)d_in[10];

    float* out  = (float*)d_out;       // out[0] = loss
    float* outs = out + 1;             // [NB][S_LEN][4] logit scratch == output_batch region
    (void)hipMemsetAsync(d_out, 0, sizeof(float), stream);   // zero loss only
    rnn_kernel<<<NB, 64, 0, stream>>>(gt, eWih, eWhh, ebih, ebhh,
                                      dWih, dWhh, dbih, dbhh, oW, ob, outs);
    loss_kernel<<<(NB * S_LEN) / 1024, 1024, 0, stream>>>(gt, outs, out);
}

// Round 9
// 2892.568 us; speedup vs baseline: 1.2157x; 1.0365x over previous
//
#include <hip/hip_runtime.h>

#define S_LEN 8192
#define NH 16
#define NV 4
#define NB 512

typedef _Float16 h2 __attribute__((ext_vector_type(2)));

#define L2E  1.4426950408889634f   // log2(e)
#define L2E2 2.8853900817779268f   // 2*log2(e)

// ---------- DPP helpers ----------
template<int R>
__device__ __forceinline__ float rotf(float v) {
    return __int_as_float(__builtin_amdgcn_mov_dpp(__float_as_int(v), 0x120 + R, 0xF, 0xF, true));
}
template<int R>
__device__ __forceinline__ h2 roth(h2 v) {    // row_ror:R on a packed half2 reg
    int i;
    __builtin_memcpy(&i, &v, 4);
    i = __builtin_amdgcn_mov_dpp(i, 0x120 + R, 0xF, 0xF, true);
    h2 o;
    __builtin_memcpy(&o, &i, 4);
    return o;
}
__device__ __forceinline__ float qxor1(float v) {  // quad_perm [1,0,3,2]
    return __int_as_float(__builtin_amdgcn_mov_dpp(__float_as_int(v), 0xB1, 0xF, 0xF, true));
}
__device__ __forceinline__ float qxor2(float v) {  // quad_perm [2,3,0,1]
    return __int_as_float(__builtin_amdgcn_mov_dpp(__float_as_int(v), 0x4E, 0xF, 0xF, true));
}
__device__ __forceinline__ float qxor3(float v) {  // quad_perm [3,2,1,0]
    return __int_as_float(__builtin_amdgcn_mov_dpp(__float_as_int(v), 0x1B, 0xF, 0xF, true));
}

__device__ __forceinline__ float fex2(float x) { return __builtin_amdgcn_exp2f(x); }
__device__ __forceinline__ float frcp(float x) { return __builtin_amdgcn_rcpf(x); }
// pre-scaled sigmoid: x already multiplied by log2(e) (folded into weights)
__device__ __forceinline__ float fsig2(float x) { return frcp(1.0f + fex2(-x)); }
__device__ __forceinline__ float4 ld4(const float* p) { return *(const float4*)p; }

// Pack two f32 to half2 via v_cvt_pkrtz_f16_f32.
__device__ __forceinline__ h2 pkh(float a, float b) {
    auto t = __builtin_amdgcn_cvt_pkrtz(a, b);
    h2 o;
    __builtin_memcpy(&o, &t, 4);
    return o;
}

// Half-broadcast-exchange (lanes i <-> i+32): after call lo = lower half's
// value everywhere, hi = upper half's value everywhere. (semantics HW-verified)
__device__ __forceinline__ void bcast32(float v, float& lo, float& hi) {
    lo = v;
    asm("v_permlane32_swap_b32 %0, %1" : "+v"(lo), "+v"(v));
    hi = v;
}
// Row-pair broadcast-exchange (lanes i <-> i+16 within each half):
// e = even-row's value in both rows of the pair, o = odd-row's value.
// (semantics HW-verified in round 5)
__device__ __forceinline__ void bcast16(float v, float& e, float& o) {
    e = v;
    asm("v_permlane16_swap_b32 %0, %1" : "+v"(e), "+v"(v));
    o = v;
}

// hp[k] = packed (h[(j+sgn*2k)&15], h[(j+sgn*(2k+1))&15]) as half2.
#define FILL_HP16(hp, h)                                      \
    do {                                                      \
        h2 p0_ = pkh((h), rotf<1>(h));                        \
        hp[0] = p0_;                                          \
        hp[1] = roth<2>(p0_);                                 \
        hp[2] = roth<4>(p0_);                                 \
        hp[3] = roth<6>(p0_);                                 \
        hp[4] = roth<8>(p0_);                                 \
        hp[5] = roth<10>(p0_);                                \
        hp[6] = roth<12>(p0_);                                \
        hp[7] = roth<14>(p0_);                                \
    } while (0)

// single-chain dots (best-measured r5 configuration)
__device__ __forceinline__ float dot8s(const h2* __restrict__ w, const h2* hp, float start) {
    float a = start;
#pragma unroll
    for (int p = 0; p < 8; ++p) a = __builtin_amdgcn_fdot2(w[p], hp[p], a, false);
    return a;
}
__device__ __forceinline__ float dot10s(const h2* __restrict__ w, const h2* hp, float start) {
    float a = start;
#pragma unroll
    for (int p = 0; p < 10; ++p) a = __builtin_amdgcn_fdot2(w[p], hp[p], a, false);
    return a;
}

// ======================= FUSED ENC+DEC, 1 element/wave, 4 roles =======================
// 512 blocks x 64 threads. Each 16-lane row computes ONE dot per step.
// Role order chosen so bcast16 delivers the shared-sigmoid input directly:
//   enc rows: 0 = r' (h+x, L2E)   1 = hn (h, L2E2)   2 = z' (h+x, L2E)  3 = inn (x, L2E2)
//   dec rows: 0 = r' (h, L2E)     1 = hn (h, L2E2)   2 = z' (h, L2E)    3 = oa (oW, exact)
// bcast16 -> e = {r' | z'} per half, o = {hn | inn-or-oa}; one fsig2 covers r AND z.
// Session conclusion: wall = ~840 cyc/step-pair serial-dependency floor
// (invariant across instr count 88-108 and element packing; VALUBusy 26%,
// HBM 0.6% — no HW pipe near roofline). This is the best-measured config.
__global__ __launch_bounds__(64, 1) void rnn_kernel(
    const float* __restrict__ gt,
    const float* __restrict__ eWih, const float* __restrict__ eWhh,
    const float* __restrict__ ebih, const float* __restrict__ ebhh,
    const float* __restrict__ dWih, const float* __restrict__ dWhh,
    const float* __restrict__ dbih, const float* __restrict__ dbhh,
    const float* __restrict__ oW,  const float* __restrict__ ob,
    float* __restrict__ outs)                 // [NB][S_LEN][4] logit scratch
{
    const int lane = threadIdx.x;
    const int j    = lane & 15;
    const int q    = j & 3;
    const int row  = lane >> 4;               // 0..3 = gate role
    const bool loH = (lane < 32);
    const int b    = blockIdx.x;

    int probe = __builtin_amdgcn_mov_dpp(j, 0x121, 0xF, 0xF, true);
    const int sgn = (probe == ((j + 1) & 15)) ? 1 : -1;

    float h = 0.0f;

    // ---------------- encoder phase ----------------
    {
        const float* gb = gt + (size_t)b * (NV * S_LEN);
        h2 w[10];
        float start;
        {
            // h-part rows of this role's weight matrix (zero for row3)
            const int g  = (row == 0) ? 0 : (row == 2) ? 1 : 2;   // r,z,n row-block in Whh/Wih
            const float schh = (row == 0 || row == 2) ? L2E : (row == 1 ? L2E2 : 0.0f);
            const float scih = (row == 0 || row == 2) ? L2E : (row == 3 ? L2E2 : 0.0f);
#pragma unroll
            for (int p = 0; p < 8; ++p) {
                int k0 = (j + sgn * (2 * p)) & 15;
                int k1 = (j + sgn * (2 * p + 1)) & 15;
                w[p] = (h2){(_Float16)(schh * eWhh[(g * NH + j) * NH + k0]),
                            (_Float16)(schh * eWhh[(g * NH + j) * NH + k1])};
            }
#pragma unroll
            for (int p = 0; p < 2; ++p) {     // x-part, k16-19 (zero for row1)
                w[8 + p] = (h2){(_Float16)(scih * eWih[(g * NH + j) * NV + 2 * p]),
                                (_Float16)(scih * eWih[(g * NH + j) * NV + 2 * p + 1])};
            }
            start = (row == 0) ? L2E  * (ebih[j] + ebhh[j])
                  : (row == 2) ? L2E  * (ebih[NH + j] + ebhh[NH + j])
                  : (row == 1) ? L2E2 * ebhh[2 * NH + j]
                               : L2E2 * ebih[2 * NH + j];
        }

        auto estep = [&](float x0, float x1, float x2, float x3) {
            h2 hp[10];
            FILL_HP16(hp, h);
            hp[8] = pkh(x0, x1);
            hp[9] = pkh(x2, x3);
            float v = dot10s(w, hp, start);
            float e, o_;
            bcast16(v, e, o_);                 // e = {r'|z'}, o_ = {hn|inn}
            float hn_, inn_;
            bcast32(o_, hn_, inn_);
            float sg = fsig2(e);               // lo: r, hi: z (shared trans)
            float r, z;
            bcast32(sg, r, z);
            float y  = fmaf(r, hn_, inn_);     // = 2*log2(e) * (inn + r*hn)
            float w2 = fsig2(y);               // = sigma(2y) -> tanh blend
            float t2 = fmaf(-2.0f, z, 2.0f);
            float tb = fmaf(z, h, z - 1.0f);
            h = fmaf(w2, t2, tb);
        };

        float4 A0 = ld4(gb + 0 * S_LEN), A1 = ld4(gb + 1 * S_LEN),
               A2 = ld4(gb + 2 * S_LEN), A3 = ld4(gb + 3 * S_LEN);
        float4 B0 = ld4(gb + 0 * S_LEN + 4), B1 = ld4(gb + 1 * S_LEN + 4),
               B2 = ld4(gb + 2 * S_LEN + 4), B3 = ld4(gb + 3 * S_LEN + 4);
        for (int t = 0; t < S_LEN; t += 8) {
            estep(A0.x, A1.x, A2.x, A3.x);
            estep(A0.y, A1.y, A2.y, A3.y);
            estep(A0.z, A1.z, A2.z, A3.z);
            estep(A0.w, A1.w, A2.w, A3.w);
            int ta = t + 8;  if (ta > S_LEN - 4) ta = S_LEN - 4;
            A0 = ld4(gb + 0 * S_LEN + ta); A1 = ld4(gb + 1 * S_LEN + ta);
            A2 = ld4(gb + 2 * S_LEN + ta); A3 = ld4(gb + 3 * S_LEN + ta);
            estep(B0.x, B1.x, B2.x, B3.x);
            estep(B0.y, B1.y, B2.y, B3.y);
            estep(B0.z, B1.z, B2.z, B3.z);
            estep(B0.w, B1.w, B2.w, B3.w);
            int tb2 = t + 12; if (tb2 > S_LEN - 4) tb2 = S_LEN - 4;
            B0 = ld4(gb + 0 * S_LEN + tb2); B1 = ld4(gb + 1 * S_LEN + tb2);
            B2 = ld4(gb + 2 * S_LEN + tb2); B3 = ld4(gb + 3 * S_LEN + tb2);
        }
    }

    // ---------------- decoder phase ----------------
    h2 w[8];
    float start;
    {
        const int g  = (row == 0) ? 0 : (row == 2) ? 1 : 2;
        const float schh = (row == 0 || row == 2) ? L2E : (row == 1 ? L2E2 : 0.0f);
#pragma unroll
        for (int p = 0; p < 8; ++p) {
            int k0 = (j + sgn * (2 * p)) & 15;
            int k1 = (j + sgn * (2 * p + 1)) & 15;
            float w0 = (row == 3) ? oW[q * NH + k0] : schh * dWhh[(g * NH + j) * NH + k0];
            float w1 = (row == 3) ? oW[q * NH + k1] : schh * dWhh[(g * NH + j) * NH + k1];
            w[p] = (h2){(_Float16)w0, (_Float16)w1};
        }
        start = (row == 0) ? L2E  * (dbih[j] + dbhh[j])
              : (row == 2) ? L2E  * (dbih[NH + j] + dbhh[NH + j])
              : (row == 1) ? L2E2 * dbhh[2 * NH + j]
                           : ob[q];
    }
    const float bNi  = dbih[2 * NH + j];
    const float bNiS = L2E2 * bNi;
    // per-class one-hot x-terms, REGISTER order m (class = m ^ q), pre-scaled.
    // SA: lo-half = r-gate x-terms, hi-half = z-gate x-terms (sig sharing).
    const int gS = loH ? 0 : 1;
    float SA[NV], KN[NV];
#pragma unroll
    for (int m = 0; m < NV; ++m) {
        int c = m ^ q;
        SA[m] = L2E * dWih[(gS * NH + j) * NV + c];
        KN[m] = L2E2 * (bNi + dWih[(2 * NH + j) * NV + c]);
    }

    int oidx = (b << 15) + q;                 // (b*S_LEN + 0)*4 + q
    const bool storer = (lane < 4);           // row0 quad0: q = lane

    // koff is a compile-time literal under #pragma unroll: store address folds
    // into the global_store immediate offset (one oidx add per 8 steps).
    auto dstep = [&](int koff) {
        h2 hp[8];
        FILL_HP16(hp, h);
        float v = dot8s(w, hp, start);
        float e, o_;
        bcast16(v, e, o_);                    // e = {r'|z'}, o_ = {hn|oa}
        float hn_, oa;
        bcast32(o_, hn_, oa);
        if (storer) outs[oidx + koff] = oa;   // logits of step t-1
        // argmax over the quad: 3 independent DPP fetches
        float ob_ = qxor1(oa);                // out[q^1]
        float oc_ = qxor2(oa);                // out[q^2]
        float od_ = qxor3(oa);                // out[q^3]
        bool cA = ob_ > oa;  float mA = fmaxf(oa, ob_);
        bool cB = od_ > oc_; float mB = fmaxf(oc_, od_);
        bool hi_ = mB > mA;
        float KA  = hi_ ? (cB ? SA[3] : SA[2]) : (cA ? SA[1] : SA[0]);
        float KN_ = hi_ ? (cB ? KN[3] : KN[2]) : (cA ? KN[1] : KN[0]);
        float sg  = fsig2(e + KA);            // lo: r, hi: z (shared trans)
        float r, z;
        bcast32(sg, r, z);
        float y   = fmaf(r, hn_, KN_);
        float w2  = fsig2(y);
        float t2  = fmaf(-2.0f, z, 2.0f);
        float tb  = fmaf(z, h, z - 1.0f);
        h = fmaf(w2, t2, tb);
    };

    // t = 0: x0 = zeros — no K terms, no store, no argmax
    {
        h2 hp[8];
        FILL_HP16(hp, h);
        float v = dot8s(w, hp, start);
        float e, o_;
        bcast16(v, e, o_);
        float hn_, oa;
        bcast32(o_, hn_, oa);
        float sg = fsig2(e);
        float r, z;
        bcast32(sg, r, z);
        float y  = fmaf(r, hn_, bNiS);
        float w2 = fsig2(y);
        float t2 = fmaf(-2.0f, z, 2.0f);
        float tb = fmaf(z, h, z - 1.0f);
        h = fmaf(w2, t2, tb);
    }
    // t = 1..8191: 8191 dsteps = 1023 x 8 + 7
    for (int u = 0; u < 8184; u += 8) {
#pragma unroll
        for (int k = 0; k < 8; ++k) dstep(k * 4);
        oidx += 32;
    }
#pragma unroll
    for (int k = 0; k < 7; ++k) dstep(k * 4);
    oidx += 28;

    // tail: logits of final step (t = S-1)
    {
        h2 hp[8];
        FILL_HP16(hp, h);
        float v = dot8s(w, hp, start);
        float e, o_;
        bcast16(v, e, o_);
        float hn_, oa;
        bcast32(o_, hn_, oa);
        if (storer) outs[oidx] = oa;
    }
}

// Epilogue: NLL over all (b,t) from stored logits + gt targets; zero the scratch.
__global__ __launch_bounds__(1024) void loss_kernel(
    const float* __restrict__ gt, float* __restrict__ outs, float* __restrict__ loss)
{
    int tid = blockIdx.x * 1024 + threadIdx.x;   // over NB*S_LEN
    int t = tid & (S_LEN - 1);
    int b = tid >> 13;
    float4 o = *(const float4*)(outs + (size_t)tid * 4);
    const float* g = gt + (size_t)b * (NV * S_LEN) + t;
    float p0 = g[0], p1 = g[S_LEN], p2 = g[2 * S_LEN], p3 = g[3 * S_LEN];
    int tg = (p1 > p0) ? 1 : 0;  float bm = fmaxf(p0, p1);
    tg = (p2 > bm) ? 2 : tg;     bm = fmaxf(p2, bm);
    tg = (p3 > bm) ? 3 : tg;
    float vt = (tg & 1) ? ((tg & 2) ? o.w : o.y) : ((tg & 2) ? o.z : o.x);
    float mx = fmaxf(fmaxf(o.x, o.y), fmaxf(o.z, o.w));
    float ss = __expf(o.x - mx) + __expf(o.y - mx) + __expf(o.z - mx) + __expf(o.w - mx);
    float v  = (mx - vt) + __logf(ss);
    *(float4*)(outs + (size_t)tid * 4) = make_float4(0.f, 0.f, 0.f, 0.f);
#pragma unroll
    for (int d = 1; d < 64; d <<= 1) v += __shfl_xor(v, d, 64);
    __shared__ float sm[16];
    int w = threadIdx.x >> 6;
    if ((threadIdx.x & 63) == 0) sm[w] = v;
    __syncthreads();
    if (threadIdx.x < 16) {
        float s = sm[threadIdx.x];
#pragma unroll
        for (int d = 1; d < 16; d <<= 1) s += __shfl_xor(s, d, 64);
        if (threadIdx.x == 0) atomicAdd(loss, s * (1.0f / NB));
    }
}

extern "C" void kernel_launch(void* const* d_in, const int* in_sizes, int n_in,
                              void* d_out, int out_size, void* d_ws, size_t ws_size,
                              hipStream_t stream) {
    (void)in_sizes; (void)n_in; (void)d_ws; (void)ws_size; (void)out_size;
    const float* gt   = (const float*)d_in[0];
    const float* eWih = (const float*)d_in[1];
    const float* eWhh = (const float*)d_in[2];
    const float* ebih = (const float*)d_in[3];
    const float* ebhh = (const float*)d_in[4];
    const float* dWih = (const float*)d_in[5];
    const float* dWhh = (const float*)d_in[6];
    const float* dbih = (const float*)d_in[7];
    const float* dbhh = (const float*)d_in[8];
    const float* oW   = (const float*)d_in[9];
    const float* ob   = (const float*)d_in[10];

    float* out  = (float*)d_out;       // out[0] = loss
    float* outs = out + 1;             // [NB][S_LEN][4] logit scratch == output_batch region
    (void)hipMemsetAsync(d_out, 0, sizeof(float), stream);   // zero loss only
    rnn_kernel<<<NB, 64, 0, stream>>>(gt, eWih, eWhh, ebih, ebhh,
                                      dWih, dWhh, dbih, dbhh, oW, ob, outs);
    loss_kernel<<<(NB * S_LEN) / 1024, 1024, 0, stream>>>(gt, outs, out);
}